// Round 1
// baseline (469.076 us; speedup 1.0000x reference)
//
#include <hip/hip_runtime.h>
#include <hip/hip_bf16.h>
#include <cstdint>
#include <cstddef>

#define NQ 8192
#define NK 8192
#define DD 64

typedef __bf16 bf16x8 __attribute__((ext_vector_type(8)));
typedef float f32x16 __attribute__((ext_vector_type(16)));
typedef unsigned short u16;

static __device__ __forceinline__ u16 f2bf(float f) {
    union { float f; uint32_t u; } v; v.f = f;
    uint32_t r = (v.u + 0x7fffu + ((v.u >> 16) & 1u)) >> 16;
    return (u16)r;
}

// ---------------- Kernel 1: L2-normalize Q and K rows -> bf16 ----------------
__global__ void k_norm(const float* __restrict__ q, const float* __restrict__ k,
                       u16* __restrict__ qn, u16* __restrict__ kn) {
    int wid  = (blockIdx.x * blockDim.x + threadIdx.x) >> 6;
    int lane = threadIdx.x & 63;                 // lane == d (D == 64)
    int nw   = (gridDim.x * blockDim.x) >> 6;
    for (int row = wid; row < 2 * NQ; row += nw) {
        const float* src = (row < NQ) ? q : k;
        u16* dst = (row < NQ) ? qn : kn;
        int r = row & (NQ - 1);
        float x = src[(size_t)r * DD + lane];
        float ss = x * x;
        #pragma unroll
        for (int m = 1; m < 64; m <<= 1) ss += __shfl_xor(ss, m, 64);
        dst[(size_t)r * DD + lane] = f2bf(x * rsqrtf(ss));
    }
}

// ---------------- Kernel 2: transpose V -> vT[d][m] bf16 ----------------
__global__ void k_transv(const float* __restrict__ v, u16* __restrict__ vT) {
    __shared__ float ts[64][65];
    int mb = blockIdx.x * 64;
    int t = threadIdx.x;
    #pragma unroll
    for (int i = 0; i < 16; i++) {
        int idx = i * 256 + t;
        int r = idx >> 6, c = idx & 63;
        ts[r][c] = v[(size_t)(mb + r) * DD + c];
    }
    __syncthreads();
    #pragma unroll
    for (int i = 0; i < 16; i++) {
        int idx = i * 256 + t;
        int d = idx >> 6, m = idx & 63;
        vT[(size_t)d * NK + mb + m] = f2bf(ts[m][d]);
    }
}

// ---------------- Kernel 3: flash pass -> inv_rowsum + res_query ----------------
// 256 blocks, each owns 32 q-rows, loops over all keys in tiles of 128.
// Wave w: QK^T for k-cols [32w,32w+32); PV for d-block (w>>1)*32, k-half (w&1)*64.
__global__ void k_flash(const u16* __restrict__ qn, const u16* __restrict__ kn,
                        const u16* __restrict__ vT, const int* __restrict__ hcp,
                        float* __restrict__ inv_rs, float* __restrict__ out_res) {
    __shared__ __align__(16) u16 qs[32 * 64];    //  4 KB, 8 chunks/row, XOR-swizzled
    __shared__ __align__(16) u16 ks[128 * 64];   // 16 KB
    __shared__ __align__(16) u16 vs[64 * 128];   // 16 KB, 16 chunks/row
    __shared__ __align__(16) u16 es[32 * 128];   //  8 KB, 16 chunks/row
    __shared__ float red[32 * 64];               //  8 KB
    __shared__ float rs_ws[4][32];
    __shared__ float inv_s[32];

    const float hc = (float)hcp[0];
    const int t = threadIdx.x;
    const int w = t >> 6;
    const int lane = t & 63;
    const int l31 = lane & 31;
    const int half = lane >> 5;
    const int qb = blockIdx.x * 32;

    // stage q block (once)
    {
        int row = t >> 3, c = t & 7;
        *reinterpret_cast<uint4*>(&qs[row * 64 + ((c ^ (row & 7)) * 8)]) =
            *reinterpret_cast<const uint4*>(&qn[(size_t)(qb + row) * DD + c * 8]);
    }

    float rs[16];
    f32x16 pv;
    #pragma unroll
    for (int i = 0; i < 16; i++) { rs[i] = 0.f; pv[i] = 0.f; }

    const int db = (w >> 1) * 32;   // PV d-block
    const int kh = (w & 1) * 64;    // PV k-half
    const int kw = w * 32;          // QK k-chunk

    for (int kb = 0; kb < NK / 128; kb++) {
        __syncthreads();   // previous iter's reads done before overwrite
        #pragma unroll
        for (int i = 0; i < 4; i++) {   // stage K tile [128][64]
            int idx = i * 256 + t;
            int row = idx >> 3, c = idx & 7;
            *reinterpret_cast<uint4*>(&ks[row * 64 + ((c ^ (row & 7)) * 8)]) =
                *reinterpret_cast<const uint4*>(&kn[(size_t)(kb * 128 + row) * DD + c * 8]);
        }
        #pragma unroll
        for (int i = 0; i < 4; i++) {   // stage vT tile [64][128]
            int idx = i * 256 + t;
            int row = idx >> 4, c = idx & 15;
            *reinterpret_cast<uint4*>(&vs[row * 128 + ((c ^ (row & 7)) * 8)]) =
                *reinterpret_cast<const uint4*>(&vT[(size_t)row * NK + kb * 128 + c * 8]);
        }
        __syncthreads();

        // QK^T: S[32q x 32k] for this wave's k-chunk
        f32x16 acc;
        #pragma unroll
        for (int i = 0; i < 16; i++) acc[i] = 0.f;
        #pragma unroll
        for (int s = 0; s < 4; s++) {
            int ca = 2 * s + half;
            bf16x8 a = *reinterpret_cast<const bf16x8*>(&qs[l31 * 64 + ((ca ^ (l31 & 7)) * 8)]);
            int kr = kw + l31;
            bf16x8 b = *reinterpret_cast<const bf16x8*>(&ks[kr * 64 + ((ca ^ (kr & 7)) * 8)]);
            acc = __builtin_amdgcn_mfma_f32_32x32x16_bf16(a, b, acc, 0, 0, 0);
        }
        // exp, rowsum accumulate, write e-tile (bf16) to LDS
        #pragma unroll
        for (int r = 0; r < 16; r++) {
            int qrow = (r & 3) + 8 * (r >> 2) + 4 * half;
            int kcol = kw + l31;
            float e = __expf(acc[r] * hc);
            rs[r] += e;
            es[qrow * 128 + (((kcol >> 3) ^ (qrow & 7)) * 8) + (kcol & 7)] = f2bf(e);
        }
        __syncthreads();

        // PV: res_unnorm[32q x 32d] partial for this wave's (d-block, k-half)
        #pragma unroll
        for (int ss = 0; ss < 4; ss++) {
            int ch = (kh >> 3) + 2 * ss + half;   // 16B-chunk index along k
            bf16x8 a = *reinterpret_cast<const bf16x8*>(&es[l31 * 128 + ((ch ^ (l31 & 7)) * 8)]);
            int dr = db + l31;
            bf16x8 b = *reinterpret_cast<const bf16x8*>(&vs[dr * 128 + ((ch ^ (dr & 7)) * 8)]);
            pv = __builtin_amdgcn_mfma_f32_32x32x16_bf16(a, b, pv, 0, 0, 0);
        }
    }

    // ---- epilogue: rowsum reduce ----
    #pragma unroll
    for (int r = 0; r < 16; r++) {
        float v = rs[r];
        v += __shfl_xor(v, 1, 64);
        v += __shfl_xor(v, 2, 64);
        v += __shfl_xor(v, 4, 64);
        v += __shfl_xor(v, 8, 64);
        v += __shfl_xor(v, 16, 64);
        if (l31 == 0) rs_ws[w][(r & 3) + 8 * (r >> 2) + 4 * half] = v;
    }
    __syncthreads();
    if (t < 32) {
        float s = rs_ws[0][t] + rs_ws[1][t] + rs_ws[2][t] + rs_ws[3][t];
        float inv = 1.0f / s;
        inv_s[t] = inv;
        inv_rs[qb + t] = inv;
    }
    // ---- res reduce across wave pairs ----
    if ((w & 1) == 0) {
        #pragma unroll
        for (int r = 0; r < 16; r++) {
            int qrow = (r & 3) + 8 * (r >> 2) + 4 * half;
            red[qrow * 64 + db + l31] = pv[r];
        }
    }
    __syncthreads();
    if ((w & 1) == 1) {
        #pragma unroll
        for (int r = 0; r < 16; r++) {
            int qrow = (r & 3) + 8 * (r >> 2) + 4 * half;
            red[qrow * 64 + db + l31] += pv[r];
        }
    }
    __syncthreads();
    #pragma unroll
    for (int i = 0; i < 8; i++) {
        int idx = i * 256 + t;
        int qq = idx >> 6, d2 = idx & 63;
        out_res[(size_t)(qb + qq) * DD + d2] = red[idx] * inv_s[qq];
    }
}

// ---------------- Kernel 4: recompute scores, write p_attn ----------------
// Block tile 128q x 64k; wave w owns 32 q-rows x 64 k-cols.
__global__ void k_pwrite(const u16* __restrict__ qn, const u16* __restrict__ kn,
                         const float* __restrict__ inv_rs, const int* __restrict__ hcp,
                         float* __restrict__ out_p) {
    __shared__ __align__(16) u16 qs[128 * 64];   // 16 KB
    __shared__ __align__(16) u16 ks[64 * 64];    //  8 KB
    __shared__ float inv2[128];

    const float hc = (float)hcp[0];
    int bid = blockIdx.x;
    int qi = bid >> 7, ki = bid & 127;
    const int qb = qi * 128, kb = ki * 64;
    const int t = threadIdx.x;
    const int w = t >> 6;
    const int l31 = (t & 63) & 31;
    const int half = (t & 63) >> 5;

    #pragma unroll
    for (int i = 0; i < 4; i++) {
        int idx = i * 256 + t;
        int row = idx >> 3, c = idx & 7;
        *reinterpret_cast<uint4*>(&qs[row * 64 + ((c ^ (row & 7)) * 8)]) =
            *reinterpret_cast<const uint4*>(&qn[(size_t)(qb + row) * DD + c * 8]);
    }
    #pragma unroll
    for (int i = 0; i < 2; i++) {
        int idx = i * 256 + t;
        int row = idx >> 3, c = idx & 7;
        *reinterpret_cast<uint4*>(&ks[row * 64 + ((c ^ (row & 7)) * 8)]) =
            *reinterpret_cast<const uint4*>(&kn[(size_t)(kb + row) * DD + c * 8]);
    }
    if (t < 128) inv2[t] = inv_rs[qb + t];
    __syncthreads();

    f32x16 acc0, acc1;
    #pragma unroll
    for (int i = 0; i < 16; i++) { acc0[i] = 0.f; acc1[i] = 0.f; }

    #pragma unroll
    for (int s = 0; s < 4; s++) {
        int ca = 2 * s + half;
        int qr = w * 32 + l31;
        bf16x8 a  = *reinterpret_cast<const bf16x8*>(&qs[qr * 64 + ((ca ^ (qr & 7)) * 8)]);
        int c0 = l31, c1 = 32 + l31;
        bf16x8 b0 = *reinterpret_cast<const bf16x8*>(&ks[c0 * 64 + ((ca ^ (c0 & 7)) * 8)]);
        bf16x8 b1 = *reinterpret_cast<const bf16x8*>(&ks[c1 * 64 + ((ca ^ (c1 & 7)) * 8)]);
        acc0 = __builtin_amdgcn_mfma_f32_32x32x16_bf16(a, b0, acc0, 0, 0, 0);
        acc1 = __builtin_amdgcn_mfma_f32_32x32x16_bf16(a, b1, acc1, 0, 0, 0);
    }

    #pragma unroll
    for (int r = 0; r < 16; r++) {
        int qq = w * 32 + (r & 3) + 8 * (r >> 2) + 4 * half;
        float iv = inv2[qq];
        float p0 = __expf(acc0[r] * hc) * iv;
        float p1 = __expf(acc1[r] * hc) * iv;
        size_t base = (size_t)(qb + qq) * NK + kb;
        out_p[base + l31] = p0;
        out_p[base + 32 + l31] = p1;
    }
}

extern "C" void kernel_launch(void* const* d_in, const int* in_sizes, int n_in,
                              void* d_out, int out_size, void* d_ws, size_t ws_size,
                              hipStream_t stream) {
    const float* q = (const float*)d_in[0];
    const float* k = (const float*)d_in[1];
    const float* v = (const float*)d_in[2];
    const int* hc = (const int*)d_in[3];

    float* out_res = (float*)d_out;
    float* out_p = out_res + (size_t)NQ * DD;

    u16* qn = (u16*)d_ws;
    u16* kn = qn + (size_t)NQ * DD;
    u16* vT = kn + (size_t)NK * DD;
    float* inv_rs = (float*)(vT + (size_t)NK * DD);

    k_norm<<<1024, 256, 0, stream>>>(q, k, qn, kn);
    k_transv<<<NK / 64, 256, 0, stream>>>(v, vT);
    k_flash<<<NQ / 32, 256, 0, stream>>>(qn, kn, vT, hc, inv_rs, out_res);
    k_pwrite<<<(NQ / 128) * (NK / 64), 256, 0, stream>>>(qn, kn, inv_rs, hc, out_p);
}

// Round 4
// 333.808 us; speedup vs baseline: 1.4052x; 1.4052x over previous
//
#include <hip/hip_runtime.h>
#include <hip/hip_bf16.h>
#include <cstdint>
#include <cstddef>

#define NQ 8192
#define NK 8192
#define DD 64
#define KSPLIT 4
#define KRANGE (NK / KSPLIT)   // 2048
#define KTILE 128

typedef __bf16 bf16x8 __attribute__((ext_vector_type(8)));
typedef float f32x16 __attribute__((ext_vector_type(16)));
typedef unsigned short u16;
typedef uint32_t u32;

static __device__ __forceinline__ u16 f2bf(float f) {
    union { float f; uint32_t u; } v; v.f = f;
    uint32_t r = (v.u + 0x7fffu + ((v.u >> 16) & 1u)) >> 16;
    return (u16)r;
}

static __device__ __forceinline__ u32 cvtpk(float lo, float hi) {
    u32 r;
    asm("v_cvt_pk_bf16_f32 %0, %1, %2" : "=v"(r) : "v"(lo), "v"(hi));
    return r;
}

#define GLOAD16(g, l)                                                          \
    __builtin_amdgcn_global_load_lds(                                          \
        (__attribute__((address_space(1))) void*)(g),                          \
        (__attribute__((address_space(3))) void*)(l), 16, 0, 0)

// ---------------- Kernel 1: L2-normalize Q and K rows -> bf16 ----------------
__global__ void k_norm(const float* __restrict__ q, const float* __restrict__ k,
                       u16* __restrict__ qn, u16* __restrict__ kn) {
    int wid  = (blockIdx.x * blockDim.x + threadIdx.x) >> 6;
    int lane = threadIdx.x & 63;                 // lane == d (D == 64)
    int nw   = (gridDim.x * blockDim.x) >> 6;
    for (int row = wid; row < 2 * NQ; row += nw) {
        const float* src = (row < NQ) ? q : k;
        u16* dst = (row < NQ) ? qn : kn;
        int r = row & (NQ - 1);
        float x = src[(size_t)r * DD + lane];
        float ss = x * x;
        #pragma unroll
        for (int m = 1; m < 64; m <<= 1) ss += __shfl_xor(ss, m, 64);
        dst[(size_t)r * DD + lane] = f2bf(x * rsqrtf(ss));
    }
}

// ---------------- Kernel 2: transpose V -> vT[d][m] bf16 ----------------
__global__ void k_transv(const float* __restrict__ v, u16* __restrict__ vT) {
    __shared__ float ts[64][65];
    int mb = blockIdx.x * 64;
    int t = threadIdx.x;
    #pragma unroll
    for (int i = 0; i < 16; i++) {
        int idx = i * 256 + t;
        int r = idx >> 6, c = idx & 63;
        ts[r][c] = v[(size_t)(mb + r) * DD + c];
    }
    __syncthreads();
    #pragma unroll
    for (int i = 0; i < 16; i++) {
        int idx = i * 256 + t;
        int d = idx >> 6, m = idx & 63;
        vT[(size_t)d * NK + mb + m] = f2bf(ts[m][d]);
    }
}

// ---------------- Kernel 3: flash pass (split-K) -> partial rowsum + PV ------
// Grid 1024: block = (qi, sp); 32 q-rows, keys [sp*2048, (sp+1)*2048).
// Swapped QK^T: mfma(K,Q) -> lane holds P[q=l31][k in regs]; PV A-frag built
// in-register via cvt_pk_bf16 + permlane32_swap (no es LDS round-trip).
__global__ __launch_bounds__(256) void
k_flash(const u16* __restrict__ qn, const u16* __restrict__ kn,
        const u16* __restrict__ vT, const int* __restrict__ hcp,
        float* __restrict__ prs, float* __restrict__ ppv) {
    __shared__ __align__(16) u16 qs[32 * 64];          // 4 KB
    __shared__ __align__(16) union SmT {
        struct { u16 ks[128 * 64]; u16 vs[64 * 128]; } a;      // 32 KB
        struct { float redA[32 * 64]; float redB[32 * 64]; } b; // 16 KB (epilogue)
    } sm;
    __shared__ float rs_ws[4][32];

    const float hc = (float)hcp[0];
    const int t = threadIdx.x;
    const int w = t >> 6;
    const int lane = t & 63;
    const int l31 = lane & 31;
    const int half = lane >> 5;
    const int qb = (blockIdx.x >> 2) * 32;
    const int sp = blockIdx.x & 3;
    const int k0 = sp * KRANGE;
    const int kw = w * 32;     // this wave's k-chunk within the 128 tile

    // stage Q once (swizzled, reg path)
    {
        int row = t >> 3, c = t & 7;
        *reinterpret_cast<uint4*>(&qs[row * 64 + ((c ^ (row & 7)) * 8)]) =
            *reinterpret_cast<const uint4*>(&qn[(size_t)(qb + row) * DD + c * 8]);
    }

    float rs_sum = 0.f;
    f32x16 pv0, pv1;
    #pragma unroll
    for (int i = 0; i < 16; i++) { pv0[i] = 0.f; pv1[i] = 0.f; }

    for (int kb = 0; kb < KRANGE / KTILE; kb++) {    // 16 iterations
        __syncthreads();
        // --- stage K tile [128][64] via global_load_lds (pre-swizzled src) ---
        const u16* ksrc = kn + (size_t)(k0 + kb * KTILE) * DD;
        #pragma unroll
        for (int i = 0; i < 4; i++) {
            int idx16 = (w * 4 + i) * 64 + lane;     // 16B-slot index
            int row = idx16 >> 3, c = idx16 & 7;
            GLOAD16(ksrc + (size_t)row * DD + ((c ^ (row & 7)) * 8),
                    &sm.a.ks[(w * 4 + i) * 512]);
        }
        // --- stage V^T tile [64][128] ---
        const u16* vsrc = vT + (size_t)(k0 + kb * KTILE);
        #pragma unroll
        for (int i = 0; i < 4; i++) {
            int idx16 = (w * 4 + i) * 64 + lane;
            int row = idx16 >> 4, c = idx16 & 15;
            GLOAD16(vsrc + (size_t)row * NK + ((c ^ (row & 7)) * 8),
                    &sm.a.vs[(w * 4 + i) * 512]);
        }
        __syncthreads();

        // --- swapped QK^T: D[k][q], lane holds q=l31, k in regs ---
        f32x16 acc;
        #pragma unroll
        for (int i = 0; i < 16; i++) acc[i] = 0.f;
        #pragma unroll
        for (int s = 0; s < 4; s++) {
            int ca = 2 * s + half;
            int kr = kw + l31;
            bf16x8 af = *reinterpret_cast<const bf16x8*>(&sm.a.ks[kr * 64 + ((ca ^ (kr & 7)) * 8)]);
            bf16x8 bf = *reinterpret_cast<const bf16x8*>(&qs[l31 * 64 + ((ca ^ (l31 & 7)) * 8)]);
            acc = __builtin_amdgcn_mfma_f32_32x32x16_bf16(af, bf, acc, 0, 0, 0);
        }
        // exp + rowsum (k is reg axis: rs per q accumulates lane-locally)
        float e[16];
        #pragma unroll
        for (int r = 0; r < 16; r++) {
            e[r] = __expf(acc[r] * hc);
            rs_sum += e[r];
        }
        // --- build PV A-fragments in-register: cvt_pk + permlane32_swap ---
        bf16x8 pa[2];
        #pragma unroll
        for (int s = 0; s < 2; s++) {
            u32 x0 = cvtpk(e[8 * s + 0], e[8 * s + 1]);
            u32 y0 = cvtpk(e[8 * s + 4], e[8 * s + 5]);
            auto r0 = __builtin_amdgcn_permlane32_swap(x0, y0, false, false);
            u32 x1 = cvtpk(e[8 * s + 2], e[8 * s + 3]);
            u32 y1 = cvtpk(e[8 * s + 6], e[8 * s + 7]);
            auto r1 = __builtin_amdgcn_permlane32_swap(x1, y1, false, false);
            union { u32 u[4]; bf16x8 v; } f;
            f.u[0] = r0[0]; f.u[1] = r1[0]; f.u[2] = r0[1]; f.u[3] = r1[1];
            pa[s] = f.v;
        }
        // --- PV: D[q][d], this wave's own 32-k chunk only ---
        #pragma unroll
        for (int s = 0; s < 2; s++) {
            int cv = (kw >> 3) + 2 * s + half;
            int vr0 = l31, vr1 = 32 + l31;
            bf16x8 b0 = *reinterpret_cast<const bf16x8*>(&sm.a.vs[vr0 * 128 + ((cv ^ (vr0 & 7)) * 8)]);
            bf16x8 b1 = *reinterpret_cast<const bf16x8*>(&sm.a.vs[vr1 * 128 + ((cv ^ (vr1 & 7)) * 8)]);
            pv0 = __builtin_amdgcn_mfma_f32_32x32x16_bf16(pa[s], b0, pv0, 0, 0, 0);
            pv1 = __builtin_amdgcn_mfma_f32_32x32x16_bf16(pa[s], b1, pv1, 0, 0, 0);
        }
    }

    // ---- epilogue: partial rowsum ----
    rs_sum += __shfl_xor(rs_sum, 32, 64);
    if (lane < 32) rs_ws[w][lane] = rs_sum;
    __syncthreads();   // also: all LDS tile reads done before aliasing sm.b
    if (t < 32)
        prs[(size_t)sp * NQ + qb + t] =
            rs_ws[0][t] + rs_ws[1][t] + rs_ws[2][t] + rs_ws[3][t];

    // ---- partial PV reduce across 4 waves ----
    float* redA = sm.b.redA;
    float* redB = sm.b.redB;
    if (w == 0) {
        #pragma unroll
        for (int r = 0; r < 16; r++) {
            int qq = (r & 3) + 8 * (r >> 2) + 4 * half;
            redA[qq * 64 + l31] = pv0[r];
            redA[qq * 64 + 32 + l31] = pv1[r];
        }
    } else if (w == 1) {
        #pragma unroll
        for (int r = 0; r < 16; r++) {
            int qq = (r & 3) + 8 * (r >> 2) + 4 * half;
            redB[qq * 64 + l31] = pv0[r];
            redB[qq * 64 + 32 + l31] = pv1[r];
        }
    }
    __syncthreads();
    if (w == 2) {
        #pragma unroll
        for (int r = 0; r < 16; r++) {
            int qq = (r & 3) + 8 * (r >> 2) + 4 * half;
            redA[qq * 64 + l31] += pv0[r];
            redA[qq * 64 + 32 + l31] += pv1[r];
        }
    } else if (w == 3) {
        #pragma unroll
        for (int r = 0; r < 16; r++) {
            int qq = (r & 3) + 8 * (r >> 2) + 4 * half;
            redB[qq * 64 + l31] += pv0[r];
            redB[qq * 64 + 32 + l31] += pv1[r];
        }
    }
    __syncthreads();
    float* dst = ppv + (size_t)sp * NQ * DD + (size_t)qb * DD;
    #pragma unroll
    for (int i = 0; i < 8; i++) {
        int idx = i * 256 + t;
        dst[idx] = redA[idx] + redB[idx];
    }
}

// ---------------- Kernel 4: reduce split-K partials ----------------
__global__ void k_reduce(const float* __restrict__ prs, const float* __restrict__ ppv,
                         float* __restrict__ inv_rs, float* __restrict__ out_res) {
    int id = blockIdx.x * blockDim.x + threadIdx.x;   // 0 .. NQ*DD-1
    int n = id >> 6, d = id & 63;
    float s = prs[n] + prs[NQ + n] + prs[2 * NQ + n] + prs[3 * NQ + n];
    float inv = 1.0f / s;
    if (d == 0) inv_rs[n] = inv;
    const size_t st = (size_t)NQ * DD;
    float v = ppv[id] + ppv[st + id] + ppv[2 * st + id] + ppv[3 * st + id];
    out_res[id] = v * inv;
}

// ---------------- Kernel 5: recompute scores, write p_attn (float4) ----------
// 64x64 tile per block; 4 waves = 4 quadrants of 32x32; LDS transpose for
// dwordx4 stores.
__global__ __launch_bounds__(256) void
k_pwrite(const u16* __restrict__ qn, const u16* __restrict__ kn,
         const float* __restrict__ inv_rs, const int* __restrict__ hcp,
         float* __restrict__ out_p) {
    __shared__ __align__(16) u16 qs2[64 * 64];   // 8 KB
    __shared__ __align__(16) u16 ks2[64 * 64];   // 8 KB
    __shared__ __align__(16) float pl[64 * 68];  // 17 KB (padded)
    __shared__ float invl[64];

    const float hc = (float)hcp[0];
    const int bid = blockIdx.x;
    const int qb = (bid >> 7) * 64;
    const int kb = (bid & 127) * 64;
    const int t = threadIdx.x;
    const int w = t >> 6;
    const int lane = t & 63;
    const int l31 = lane & 31;
    const int half = lane >> 5;

    #pragma unroll
    for (int i = 0; i < 2; i++) {
        int idx16 = (w * 2 + i) * 64 + lane;
        int row = idx16 >> 3, c = idx16 & 7;
        GLOAD16(qn + (size_t)(qb + row) * DD + ((c ^ (row & 7)) * 8),
                &qs2[(w * 2 + i) * 512]);
        GLOAD16(kn + (size_t)(kb + row) * DD + ((c ^ (row & 7)) * 8),
                &ks2[(w * 2 + i) * 512]);
    }
    if (t < 64) invl[t] = inv_rs[qb + t];
    __syncthreads();

    const int wq = (w >> 1) * 32, wk = (w & 1) * 32;
    f32x16 acc;
    #pragma unroll
    for (int i = 0; i < 16; i++) acc[i] = 0.f;
    #pragma unroll
    for (int s = 0; s < 4; s++) {
        int ca = 2 * s + half;
        int qr = wq + l31, kr = wk + l31;
        bf16x8 a = *reinterpret_cast<const bf16x8*>(&qs2[qr * 64 + ((ca ^ (qr & 7)) * 8)]);
        bf16x8 b = *reinterpret_cast<const bf16x8*>(&ks2[kr * 64 + ((ca ^ (kr & 7)) * 8)]);
        acc = __builtin_amdgcn_mfma_f32_32x32x16_bf16(a, b, acc, 0, 0, 0);
    }
    #pragma unroll
    for (int r = 0; r < 16; r++) {
        int qq = wq + (r & 3) + 8 * (r >> 2) + 4 * half;
        pl[qq * 68 + wk + l31] = __expf(acc[r] * hc) * invl[qq];
    }
    __syncthreads();
    #pragma unroll
    for (int i = 0; i < 4; i++) {
        int idx = i * 256 + t;          // 1024 float4s
        int row = idx >> 4, c4 = idx & 15;
        float4 vv = *reinterpret_cast<const float4*>(&pl[row * 68 + c4 * 4]);
        *reinterpret_cast<float4*>(&out_p[(size_t)(qb + row) * NK + kb + c4 * 4]) = vv;
    }
}

extern "C" void kernel_launch(void* const* d_in, const int* in_sizes, int n_in,
                              void* d_out, int out_size, void* d_ws, size_t ws_size,
                              hipStream_t stream) {
    const float* q = (const float*)d_in[0];
    const float* k = (const float*)d_in[1];
    const float* v = (const float*)d_in[2];
    const int* hc = (const int*)d_in[3];

    float* out_res = (float*)d_out;
    float* out_p = out_res + (size_t)NQ * DD;

    char* wsb = (char*)d_ws;
    u16* qn = (u16*)wsb;
    u16* kn = qn + (size_t)NQ * DD;
    u16* vT = kn + (size_t)NK * DD;
    float* inv_rs = (float*)(vT + (size_t)NK * DD);

    const size_t base_need = 3 * (size_t)NQ * DD * 2 + (size_t)NQ * 4;
    const size_t extra_need = (size_t)KSPLIT * NQ * 4 + (size_t)KSPLIT * NQ * DD * 4;
    char* extra = (ws_size >= base_need + extra_need)
                      ? wsb + base_need
                      : (char*)out_p + ((size_t)NQ * NK * 4 - extra_need);
    float* prs = (float*)extra;                 // [KSPLIT][NQ]
    float* ppv = prs + (size_t)KSPLIT * NQ;     // [KSPLIT][NQ][DD]

    k_norm<<<1024, 256, 0, stream>>>(q, k, qn, kn);
    k_transv<<<NK / 64, 256, 0, stream>>>(v, vT);
    k_flash<<<(NQ / 32) * KSPLIT, 256, 0, stream>>>(qn, kn, vT, hc, prs, ppv);
    k_reduce<<<(NQ * DD) / 256, 256, 0, stream>>>(prs, ppv, inv_rs, out_res);
    k_pwrite<<<(NQ / 64) * (NK / 64), 256, 0, stream>>>(qn, kn, inv_rs, hc, out_p);
}